// Round 4
// baseline (190.326 us; speedup 1.0000x reference)
//
#include <hip/hip_runtime.h>

#define NT 16384
#define D  2048
#define E  64

typedef _Float16 half8 __attribute__((ext_vector_type(8)));
typedef float f32x4 __attribute__((ext_vector_type(4)));

// ---- prep: W[k][e] fp32 -> W^T panes [e][k] f16 hi/lo (exact split, w = hi + lo/2048) ----
__global__ __launch_bounds__(256) void router_prep(const float* __restrict__ W,
                                                   _Float16* __restrict__ wthi,
                                                   _Float16* __restrict__ wtlo) {
    __shared__ _Float16 lhi[64 * 128];
    __shared__ _Float16 llo[64 * 128];
    const int tid = threadIdx.x;
    const int k0  = blockIdx.x * 128;
    #pragma unroll
    for (int i = 0; i < 8; ++i) {
        const int fid = tid + i * 256;       // 0..2047
        const int kr  = fid >> 4;            // 0..127
        const int e4  = (fid & 15) * 4;
        const float4 v = *(const float4*)&W[(size_t)(k0 + kr) * E + e4];
        const float vv[4] = {v.x, v.y, v.z, v.w};
        #pragma unroll
        for (int j = 0; j < 4; ++j) {
            float hf = (float)(_Float16)vv[j];
            hf = (fabsf(hf) < 6.1035156e-5f) ? 0.f : hf;   // FTZ guard
            lhi[(e4 + j) * 128 + kr] = (_Float16)hf;
            llo[(e4 + j) * 128 + kr] = (_Float16)((vv[j] - hf) * 2048.f);
        }
    }
    __syncthreads();
    #pragma unroll
    for (int i = 0; i < 4; ++i) {
        const int cid = tid + i * 256;       // 0..1023
        const int e   = cid >> 4;
        const int c8  = (cid & 15) * 8;
        *(half8*)&wthi[(size_t)e * D + k0 + c8] = *(const half8*)&lhi[e * 128 + c8];
        *(half8*)&wtlo[(size_t)e * D + k0 + c8] = *(const half8*)&llo[e * 128 + c8];
    }
}

// ---- main: 16 tokens/block, 4 waves split K (512 each); no LDS in K-loop ----
__global__ __launch_bounds__(256, 4) void router_main(const float* __restrict__ x,
                                                      const _Float16* __restrict__ wthi,
                                                      const _Float16* __restrict__ wtlo,
                                                      const float* __restrict__ bias,
                                                      float* __restrict__ out,
                                                      float* __restrict__ ws) {
    __shared__ float red[4][16][64];   // [wave][token][expert] partial logits

    const int tid  = threadIdx.x;
    const int lane = tid & 63;
    const int w    = tid >> 6;     // wave = K-chunk 0..3
    const int g    = lane >> 4;    // 0..3
    const int c    = lane & 15;    // token within block / fragment col
    const int t0   = blockIdx.x * 16;

    const float*    xp  = &x[(size_t)(t0 + c) * D + w * 512 + g * 8];
    const _Float16* whp = &wthi[(size_t)c * D + w * 512 + g * 8];
    const _Float16* wlp = &wtlo[(size_t)c * D + w * 512 + g * 8];

    f32x4 am[4] = {{0.f,0.f,0.f,0.f},{0.f,0.f,0.f,0.f},{0.f,0.f,0.f,0.f},{0.f,0.f,0.f,0.f}};
    f32x4 ac[4] = {{0.f,0.f,0.f,0.f},{0.f,0.f,0.f,0.f},{0.f,0.f,0.f,0.f},{0.f,0.f,0.f,0.f}};

    float4 xa0 = *(const float4*)(xp);
    float4 xa1 = *(const float4*)(xp + 4);
    #pragma unroll 2
    for (int t = 0; t < 16; ++t) {
        float4 xb0, xb1;
        if (t + 1 < 16) {                      // prefetch next 32-k tile
            xb0 = *(const float4*)(xp + (t + 1) * 32);
            xb1 = *(const float4*)(xp + (t + 1) * 32 + 4);
        }
        half8 bh, bl;
        const float xv[8] = {xa0.x, xa0.y, xa0.z, xa0.w, xa1.x, xa1.y, xa1.z, xa1.w};
        #pragma unroll
        for (int j = 0; j < 8; ++j) {
            const float hf = (float)(_Float16)xv[j];
            bh[j] = (_Float16)hf;
            bl[j] = (_Float16)((xv[j] - hf) * 2048.f);
        }
        #pragma unroll
        for (int m = 0; m < 4; ++m) {
            const half8 ah = *(const half8*)(whp + (size_t)m * 16 * D + t * 32);
            const half8 al = *(const half8*)(wlp + (size_t)m * 16 * D + t * 32);
            am[m] = __builtin_amdgcn_mfma_f32_16x16x32_f16(ah, bh, am[m], 0, 0, 0);
            ac[m] = __builtin_amdgcn_mfma_f32_16x16x32_f16(ah, bl, ac[m], 0, 0, 0);
            ac[m] = __builtin_amdgcn_mfma_f32_16x16x32_f16(al, bh, ac[m], 0, 0, 0);
        }
        xa0 = xb0; xa1 = xb1;
    }

    // combine hi/lo accumulators, write partials
    #pragma unroll
    for (int m = 0; m < 4; ++m) {
        f32x4 p;
        #pragma unroll
        for (int r = 0; r < 4; ++r) p[r] = am[m][r] + ac[m][r] * (1.f / 2048.f);
        *(f32x4*)&red[w][c][m * 16 + g * 4] = p;
    }
    __syncthreads();

    if (w != 0) return;

    // ---- epilogue (wave 0): lane(g,c) holds experts e=m*16+g*4+r for token t0+c ----
    const int tg = t0 + c;
    float lg[4][4];
    #pragma unroll
    for (int m = 0; m < 4; ++m) {
        f32x4 s = *(const f32x4*)&red[0][c][m * 16 + g * 4];
        #pragma unroll
        for (int w2 = 1; w2 < 4; ++w2) {
            const f32x4 q = *(const f32x4*)&red[w2][c][m * 16 + g * 4];
            #pragma unroll
            for (int r = 0; r < 4; ++r) s[r] += q[r];
        }
        #pragma unroll
        for (int r = 0; r < 4; ++r) lg[m][r] = s[r] + bias[m * 16 + g * 4 + r];
    }

    // local top-2 over this lane's 16 experts
    float v1 = -3.4e38f, v2 = -3.4e38f; int i1 = 0, i2 = 0;
    #pragma unroll
    for (int m = 0; m < 4; ++m)
        #pragma unroll
        for (int r = 0; r < 4; ++r) {
            const float v = lg[m][r];
            const int   e = m * 16 + g * 4 + r;
            if (v > v1) { v2 = v1; i2 = i1; v1 = v; i1 = e; }
            else if (v > v2) { v2 = v; i2 = e; }
        }
    // merge across the 4 lanes (g) holding this token
    #pragma unroll
    for (int mask = 16; mask <= 32; mask <<= 1) {
        const float ov1 = __shfl_xor(v1, mask, 64); const int oi1 = __shfl_xor(i1, mask, 64);
        const float ov2 = __shfl_xor(v2, mask, 64); const int oi2 = __shfl_xor(i2, mask, 64);
        const bool oTop = (ov1 > v1) || (ov1 == v1 && oi1 < i1);
        if (oTop) {
            const bool k2 = (v1 > ov2) || (v1 == ov2 && i1 < oi2);
            v2 = k2 ? v1 : ov2; i2 = k2 ? i1 : oi2;
            v1 = ov1; i1 = oi1;
        } else {
            const bool k2 = (ov1 > v2) || (ov1 == v2 && oi1 < i2);
            v2 = k2 ? ov1 : v2; i2 = k2 ? oi1 : i2;
        }
    }

    // softmax (max = v1)
    float s = 0.f;
    #pragma unroll
    for (int m = 0; m < 4; ++m)
        #pragma unroll
        for (int r = 0; r < 4; ++r) { lg[m][r] = expf(lg[m][r] - v1); s += lg[m][r]; }
    s += __shfl_xor(s, 16, 64);
    s += __shfl_xor(s, 32, 64);
    const float inv = 1.f / s;

    // normalized probs -> per-expert sums across the 16 tokens (reduce over c)
    #pragma unroll
    for (int m = 0; m < 4; ++m)
        #pragma unroll
        for (int r = 0; r < 4; ++r) {
            lg[m][r] *= inv;
            #pragma unroll
            for (int mask = 1; mask <= 8; mask <<= 1)
                lg[m][r] += __shfl_xor(lg[m][r], mask, 64);
        }
    if (c == 0) {
        #pragma unroll
        for (int m = 0; m < 4; ++m)
            #pragma unroll
            for (int r = 0; r < 4; ++r)
                atomicAdd(&ws[m * 16 + g * 4 + r], lg[m][r]);
    }
    if (g == 0) {   // one leader lane per token
        const float p2 = expf(v2 - v1) * inv;
        out[tg * 2 + 0] = (float)i1;
        out[tg * 2 + 1] = (float)i2;
        out[2 * NT + tg * 2 + 0] = inv;     // p1 = exp(0) / s
        out[2 * NT + tg * 2 + 1] = p2;
        atomicAdd(&ws[E + i1], 1.f);
        atomicAdd(&ws[E + i2], 1.f);
    }
}

__global__ void router_aux(const float* __restrict__ ws, float* __restrict__ out) {
    const int e = threadIdx.x;
    float v = ws[e] * ws[E + e] * (1.0f / NT) * (1.0f / NT);
    #pragma unroll
    for (int off = 32; off > 0; off >>= 1) v += __shfl_down(v, off);
    if (e == 0) out[NT * 2 * 2] = (float)E * v;
}

extern "C" void kernel_launch(void* const* d_in, const int* in_sizes, int n_in,
                              void* d_out, int out_size, void* d_ws, size_t ws_size,
                              hipStream_t stream) {
    const float* x = (const float*)d_in[0];
    const float* W = (const float*)d_in[1];
    const float* b = (const float*)d_in[2];
    float* out = (float*)d_out;
    float* ws  = (float*)d_ws;

    // ws layout: [0,512B) psum+cnt accumulators; [1KB, 1KB+256KB) wthi; then wtlo
    _Float16* wthi = (_Float16*)((char*)d_ws + 1024);
    _Float16* wtlo = (_Float16*)((char*)d_ws + 1024 + D * E * sizeof(_Float16));

    hipMemsetAsync(d_ws, 0, 2 * E * sizeof(float), stream);
    router_prep<<<dim3(D / 128), dim3(256), 0, stream>>>(W, wthi, wtlo);
    router_main<<<dim3(NT / 16), dim3(256), 0, stream>>>(x, wthi, wtlo, b, out, ws);
    router_aux<<<dim3(1), dim3(E), 0, stream>>>(ws, out);
}

// Round 5
// 166.487 us; speedup vs baseline: 1.1432x; 1.1432x over previous
//
#include <hip/hip_runtime.h>

#define NT 16384
#define D  2048
#define E  64

typedef _Float16 half8 __attribute__((ext_vector_type(8)));
typedef float f32x4 __attribute__((ext_vector_type(4)));

// ---- prep: W[k][e] fp32 -> W^T hi/lo panes in MFMA-fragment order ----
// pane offset(k,e) = (((kc*TPC + t)*4 + m)*16 + c)*32 + g*8 + j
//   kc=k/KCH, t=(k%KCH)/32, g=(k%32)/8, j=k%8, m=e/16, c=e%16
// so a wave's fragment load (fixed kc,t,m; lanes (g,c)) is one contiguous 1KB segment.
__global__ __launch_bounds__(256) void router_prep(const float* __restrict__ W,
                                                   _Float16* __restrict__ wthi,
                                                   _Float16* __restrict__ wtlo,
                                                   int KCH) {
    const int id  = blockIdx.x * 256 + threadIdx.x;  // 0..32767
    const int k   = id >> 4;
    const int e4  = (id & 15) << 2;
    const int TPC = KCH >> 5;
    const int kc  = k / KCH;
    const int kr  = k % KCH;
    const int t   = kr >> 5;
    const int g   = (kr >> 3) & 3;
    const int j   = kr & 7;
    const float4 v = *(const float4*)&W[(size_t)k * E + e4];
    const float vv[4] = {v.x, v.y, v.z, v.w};
    #pragma unroll
    for (int i = 0; i < 4; ++i) {
        const int e = e4 + i;
        const int m = e >> 4, c = e & 15;
        const size_t off = ((((size_t)(kc * TPC + t) * 4 + m) * 16 + c) * 32) + g * 8 + j;
        float hf = (float)(_Float16)vv[i];
        hf = (fabsf(hf) < 6.1035156e-5f) ? 0.f : hf;   // FTZ guard
        wthi[off] = (_Float16)hf;
        wtlo[off] = (_Float16)((vv[i] - hf) * 2048.f);
    }
}

// ---- phase 1: independent waves, 32 tokens x K-chunk each, no LDS, no barriers ----
template<int S>
__global__ __launch_bounds__(256, 3) void router_gemm(const float* __restrict__ x,
                                                      const _Float16* __restrict__ wthi,
                                                      const _Float16* __restrict__ wtlo,
                                                      float* __restrict__ part) {
    constexpr int KCH = D / S;
    constexpr int TPC = KCH / 32;
    const int tid  = threadIdx.x;
    const int lane = tid & 63;
    const int w    = tid >> 6;
    const int g    = lane >> 4;
    const int c    = lane & 15;
    const int wid  = blockIdx.x * 4 + w;      // 0 .. (NT/32)*S - 1
    const int kc   = wid % S;
    const int tg   = wid / S;
    const int t0   = tg * 32;

    const float* xp0 = &x[(size_t)(t0 + c) * D + kc * KCH + g * 8];
    const float* xp1 = &x[(size_t)(t0 + 16 + c) * D + kc * KCH + g * 8];
    const _Float16* whp = &wthi[(size_t)kc * TPC * 2048 + c * 32 + g * 8];
    const _Float16* wlp = &wtlo[(size_t)kc * TPC * 2048 + c * 32 + g * 8];

    f32x4 am[2][4], ac[2][4];
    #pragma unroll
    for (int tt = 0; tt < 2; ++tt)
        #pragma unroll
        for (int m = 0; m < 4; ++m) {
            am[tt][m] = (f32x4){0.f, 0.f, 0.f, 0.f};
            ac[tt][m] = (f32x4){0.f, 0.f, 0.f, 0.f};
        }

    float4 ca0 = *(const float4*)xp0, ca1 = *(const float4*)(xp0 + 4);
    float4 cb0 = *(const float4*)xp1, cb1 = *(const float4*)(xp1 + 4);

    #pragma unroll 1
    for (int t = 0; t < TPC; ++t) {
        float4 na0, na1, nb0, nb1;
        if (t + 1 < TPC) {   // uniform scalar branch; prefetch next x tile
            na0 = *(const float4*)(xp0 + (t + 1) * 32);
            na1 = *(const float4*)(xp0 + (t + 1) * 32 + 4);
            nb0 = *(const float4*)(xp1 + (t + 1) * 32);
            nb1 = *(const float4*)(xp1 + (t + 1) * 32 + 4);
        }
        half8 bh0, bl0, bh1, bl1;
        {
            const float xv0[8] = {ca0.x, ca0.y, ca0.z, ca0.w, ca1.x, ca1.y, ca1.z, ca1.w};
            const float xv1[8] = {cb0.x, cb0.y, cb0.z, cb0.w, cb1.x, cb1.y, cb1.z, cb1.w};
            #pragma unroll
            for (int j = 0; j < 8; ++j) {
                float h0 = (float)(_Float16)xv0[j];
                bh0[j] = (_Float16)h0;  bl0[j] = (_Float16)((xv0[j] - h0) * 2048.f);
                float h1 = (float)(_Float16)xv1[j];
                bh1[j] = (_Float16)h1;  bl1[j] = (_Float16)((xv1[j] - h1) * 2048.f);
            }
        }
        #pragma unroll
        for (int m = 0; m < 4; ++m) {
            const half8 ah = *(const half8*)(whp + (size_t)(t * 4 + m) * 512);
            const half8 al = *(const half8*)(wlp + (size_t)(t * 4 + m) * 512);
            am[0][m] = __builtin_amdgcn_mfma_f32_16x16x32_f16(ah, bh0, am[0][m], 0, 0, 0);
            ac[0][m] = __builtin_amdgcn_mfma_f32_16x16x32_f16(ah, bl0, ac[0][m], 0, 0, 0);
            ac[0][m] = __builtin_amdgcn_mfma_f32_16x16x32_f16(al, bh0, ac[0][m], 0, 0, 0);
            am[1][m] = __builtin_amdgcn_mfma_f32_16x16x32_f16(ah, bh1, am[1][m], 0, 0, 0);
            ac[1][m] = __builtin_amdgcn_mfma_f32_16x16x32_f16(ah, bl1, ac[1][m], 0, 0, 0);
            ac[1][m] = __builtin_amdgcn_mfma_f32_16x16x32_f16(al, bh1, ac[1][m], 0, 0, 0);
        }
        ca0 = na0; ca1 = na1; cb0 = nb0; cb1 = nb1;
    }

    // store fp32 partials: part[kc][tok][e]
    #pragma unroll
    for (int tt = 0; tt < 2; ++tt) {
        const int tok = t0 + tt * 16 + c;
        float* dst = &part[((size_t)kc * NT + tok) * 64 + g * 4];
        #pragma unroll
        for (int m = 0; m < 4; ++m) {
            f32x4 p;
            #pragma unroll
            for (int r = 0; r < 4; ++r) p[r] = am[tt][m][r] + ac[tt][m][r] * (1.f / 2048.f);
            *(f32x4*)(dst + m * 16) = p;
        }
    }
}

// ---- phase 2: sum partials, top-2 + softmax + aux accumulation (round-3 proven epilogue) ----
__global__ __launch_bounds__(256) void router_top(const float* __restrict__ part,
                                                  const float* __restrict__ bias,
                                                  float* __restrict__ out,
                                                  float* __restrict__ ws, int S) {
    const int tid  = threadIdx.x;
    const int lane = tid & 63;
    const int w    = tid >> 6;
    const int g    = lane >> 4;
    const int c    = lane & 15;
    const int tok  = blockIdx.x * 64 + w * 16 + c;

    float lg[4][4];
    #pragma unroll
    for (int m = 0; m < 4; ++m) {
        f32x4 s = {0.f, 0.f, 0.f, 0.f};
        for (int kc = 0; kc < S; ++kc) {
            const f32x4 q = *(const f32x4*)&part[((size_t)kc * NT + tok) * 64 + m * 16 + g * 4];
            #pragma unroll
            for (int r = 0; r < 4; ++r) s[r] += q[r];
        }
        #pragma unroll
        for (int r = 0; r < 4; ++r) lg[m][r] = s[r] + bias[m * 16 + g * 4 + r];
    }

    // local top-2 over this lane's 16 experts
    float v1 = -3.4e38f, v2 = -3.4e38f; int i1 = 0, i2 = 0;
    #pragma unroll
    for (int m = 0; m < 4; ++m)
        #pragma unroll
        for (int r = 0; r < 4; ++r) {
            const float v = lg[m][r];
            const int   e = m * 16 + g * 4 + r;
            if (v > v1) { v2 = v1; i2 = i1; v1 = v; i1 = e; }
            else if (v > v2) { v2 = v; i2 = e; }
        }
    // merge across the 4 lanes (g) holding this token
    #pragma unroll
    for (int mask = 16; mask <= 32; mask <<= 1) {
        const float ov1 = __shfl_xor(v1, mask, 64); const int oi1 = __shfl_xor(i1, mask, 64);
        const float ov2 = __shfl_xor(v2, mask, 64); const int oi2 = __shfl_xor(i2, mask, 64);
        const bool oTop = (ov1 > v1) || (ov1 == v1 && oi1 < i1);
        if (oTop) {
            const bool k2 = (v1 > ov2) || (v1 == ov2 && i1 < oi2);
            v2 = k2 ? v1 : ov2; i2 = k2 ? i1 : oi2;
            v1 = ov1; i1 = oi1;
        } else {
            const bool k2 = (ov1 > v2) || (ov1 == v2 && oi1 < i2);
            v2 = k2 ? ov1 : v2; i2 = k2 ? oi1 : i2;
        }
    }

    // softmax (max = v1)
    float s = 0.f;
    #pragma unroll
    for (int m = 0; m < 4; ++m)
        #pragma unroll
        for (int r = 0; r < 4; ++r) { lg[m][r] = expf(lg[m][r] - v1); s += lg[m][r]; }
    s += __shfl_xor(s, 16, 64);
    s += __shfl_xor(s, 32, 64);
    const float inv = 1.f / s;

    // normalized probs -> per-expert sums across the 16 tokens (reduce over c)
    #pragma unroll
    for (int m = 0; m < 4; ++m)
        #pragma unroll
        for (int r = 0; r < 4; ++r) {
            lg[m][r] *= inv;
            #pragma unroll
            for (int mask = 1; mask <= 8; mask <<= 1)
                lg[m][r] += __shfl_xor(lg[m][r], mask, 64);
        }
    if (c == 0) {
        #pragma unroll
        for (int m = 0; m < 4; ++m)
            #pragma unroll
            for (int r = 0; r < 4; ++r)
                atomicAdd(&ws[m * 16 + g * 4 + r], lg[m][r]);
    }
    if (g == 0) {   // one leader lane per token
        const float p2 = expf(v2 - v1) * inv;
        out[tok * 2 + 0] = (float)i1;
        out[tok * 2 + 1] = (float)i2;
        out[2 * NT + tok * 2 + 0] = inv;     // p1 = exp(0)/s
        out[2 * NT + tok * 2 + 1] = p2;
        atomicAdd(&ws[E + i1], 1.f);
        atomicAdd(&ws[E + i2], 1.f);
    }
}

__global__ void router_aux(const float* __restrict__ ws, float* __restrict__ out) {
    const int e = threadIdx.x;
    float v = ws[e] * ws[E + e] * (1.0f / NT) * (1.0f / NT);
    #pragma unroll
    for (int off = 32; off > 0; off >>= 1) v += __shfl_down(v, off);
    if (e == 0) out[NT * 2 * 2] = (float)E * v;
}

extern "C" void kernel_launch(void* const* d_in, const int* in_sizes, int n_in,
                              void* d_out, int out_size, void* d_ws, size_t ws_size,
                              hipStream_t stream) {
    const float* x = (const float*)d_in[0];
    const float* W = (const float*)d_in[1];
    const float* b = (const float*)d_in[2];
    float* out = (float*)d_out;

    // ws layout: [0,1KB) psum+cnt accumulators; [1KB, 1KB+512KB) W panes; then partials
    char* base = (char*)d_ws;
    float*    acc  = (float*)base;
    _Float16* wthi = (_Float16*)(base + 1024);
    _Float16* wtlo = wthi + (size_t)D * E;
    float*    part = (float*)(base + 1024 + 2 * (size_t)D * E * sizeof(_Float16));
    const size_t head = 1024 + 2 * (size_t)D * E * sizeof(_Float16);

    int S = 8;   // K-split factor; shrink if workspace is small
    while (S > 1 && head + (size_t)S * NT * E * sizeof(float) > ws_size) S >>= 1;

    hipMemsetAsync(d_ws, 0, 1024, stream);
    router_prep<<<dim3(128), dim3(256), 0, stream>>>(W, wthi, wtlo, D / S);
    const int nblk = (NT / 32) * S / 4;
    switch (S) {
        case 8: router_gemm<8><<<dim3(nblk), dim3(256), 0, stream>>>(x, wthi, wtlo, part); break;
        case 4: router_gemm<4><<<dim3(nblk), dim3(256), 0, stream>>>(x, wthi, wtlo, part); break;
        case 2: router_gemm<2><<<dim3(nblk), dim3(256), 0, stream>>>(x, wthi, wtlo, part); break;
        default: router_gemm<1><<<dim3(nblk), dim3(256), 0, stream>>>(x, wthi, wtlo, part); break;
    }
    router_top<<<dim3(NT / 64), dim3(256), 0, stream>>>(part, b, out, acc, S);
    router_aux<<<dim3(1), dim3(E), 0, stream>>>(acc, out);
}

// Round 6
// 92.662 us; speedup vs baseline: 2.0540x; 1.7967x over previous
//
#include <hip/hip_runtime.h>

#define NT 16384
#define D  2048
#define E  64
#define NW (NT / 16)   // 1024 phase-2 waves

typedef _Float16 half8 __attribute__((ext_vector_type(8)));
typedef float f32x4 __attribute__((ext_vector_type(4)));

// ---- prep: W[k][e] fp32 -> W^T hi/lo panes in MFMA-fragment order ----
// pane offset(k,e) = (((kc*TPC + t)*4 + m)*16 + c)*32 + g*8 + j
__global__ __launch_bounds__(256) void router_prep(const float* __restrict__ W,
                                                   _Float16* __restrict__ wthi,
                                                   _Float16* __restrict__ wtlo,
                                                   int KCH) {
    const int id  = blockIdx.x * 256 + threadIdx.x;  // 0..32767
    const int k   = id >> 4;
    const int e4  = (id & 15) << 2;
    const int TPC = KCH >> 5;
    const int kc  = k / KCH;
    const int kr  = k % KCH;
    const int t   = kr >> 5;
    const int g   = (kr >> 3) & 3;
    const int j   = kr & 7;
    const float4 v = *(const float4*)&W[(size_t)k * E + e4];
    const float vv[4] = {v.x, v.y, v.z, v.w};
    #pragma unroll
    for (int i = 0; i < 4; ++i) {
        const int e = e4 + i;
        const int m = e >> 4, c = e & 15;
        const size_t off = ((((size_t)(kc * TPC + t) * 4 + m) * 16 + c) * 32) + g * 8 + j;
        float hf = (float)(_Float16)vv[i];
        hf = (fabsf(hf) < 6.1035156e-5f) ? 0.f : hf;   // FTZ guard
        wthi[off] = (_Float16)hf;
        wtlo[off] = (_Float16)((vv[i] - hf) * 2048.f);
    }
}

// ---- phase 1: independent waves, 32 tokens x K-chunk each, no LDS, no barriers ----
// partials layout: part[(kc*4+m)*NT + tok][16] -> contiguous 1KB per wave-store/load
template<int S>
__global__ __launch_bounds__(256, 3) void router_gemm(const float* __restrict__ x,
                                                      const _Float16* __restrict__ wthi,
                                                      const _Float16* __restrict__ wtlo,
                                                      float* __restrict__ part) {
    constexpr int KCH = D / S;
    constexpr int TPC = KCH / 32;
    const int tid  = threadIdx.x;
    const int lane = tid & 63;
    const int w    = tid >> 6;
    const int g    = lane >> 4;
    const int c    = lane & 15;
    const int wid  = blockIdx.x * 4 + w;      // 0 .. (NT/32)*S - 1
    const int kc   = wid % S;
    const int tg   = wid / S;
    const int t0   = tg * 32;

    const float* xp0 = &x[(size_t)(t0 + c) * D + kc * KCH + g * 8];
    const float* xp1 = &x[(size_t)(t0 + 16 + c) * D + kc * KCH + g * 8];
    const _Float16* whp = &wthi[(size_t)kc * TPC * 2048 + c * 32 + g * 8];
    const _Float16* wlp = &wtlo[(size_t)kc * TPC * 2048 + c * 32 + g * 8];

    f32x4 am[2][4], ac[2][4];
    #pragma unroll
    for (int tt = 0; tt < 2; ++tt)
        #pragma unroll
        for (int m = 0; m < 4; ++m) {
            am[tt][m] = (f32x4){0.f, 0.f, 0.f, 0.f};
            ac[tt][m] = (f32x4){0.f, 0.f, 0.f, 0.f};
        }

    float4 ca0 = *(const float4*)xp0, ca1 = *(const float4*)(xp0 + 4);
    float4 cb0 = *(const float4*)xp1, cb1 = *(const float4*)(xp1 + 4);

    #pragma unroll 1
    for (int t = 0; t < TPC; ++t) {
        float4 na0, na1, nb0, nb1;
        if (t + 1 < TPC) {   // uniform scalar branch; prefetch next x tile
            na0 = *(const float4*)(xp0 + (t + 1) * 32);
            na1 = *(const float4*)(xp0 + (t + 1) * 32 + 4);
            nb0 = *(const float4*)(xp1 + (t + 1) * 32);
            nb1 = *(const float4*)(xp1 + (t + 1) * 32 + 4);
        }
        half8 bh0, bl0, bh1, bl1;
        {
            const float xv0[8] = {ca0.x, ca0.y, ca0.z, ca0.w, ca1.x, ca1.y, ca1.z, ca1.w};
            const float xv1[8] = {cb0.x, cb0.y, cb0.z, cb0.w, cb1.x, cb1.y, cb1.z, cb1.w};
            #pragma unroll
            for (int j = 0; j < 8; ++j) {
                float h0 = (float)(_Float16)xv0[j];
                bh0[j] = (_Float16)h0;  bl0[j] = (_Float16)((xv0[j] - h0) * 2048.f);
                float h1 = (float)(_Float16)xv1[j];
                bh1[j] = (_Float16)h1;  bl1[j] = (_Float16)((xv1[j] - h1) * 2048.f);
            }
        }
        #pragma unroll
        for (int m = 0; m < 4; ++m) {
            const half8 ah = *(const half8*)(whp + (size_t)(t * 4 + m) * 512);
            const half8 al = *(const half8*)(wlp + (size_t)(t * 4 + m) * 512);
            am[0][m] = __builtin_amdgcn_mfma_f32_16x16x32_f16(ah, bh0, am[0][m], 0, 0, 0);
            ac[0][m] = __builtin_amdgcn_mfma_f32_16x16x32_f16(ah, bl0, ac[0][m], 0, 0, 0);
            ac[0][m] = __builtin_amdgcn_mfma_f32_16x16x32_f16(al, bh0, ac[0][m], 0, 0, 0);
            am[1][m] = __builtin_amdgcn_mfma_f32_16x16x32_f16(ah, bh1, am[1][m], 0, 0, 0);
            ac[1][m] = __builtin_amdgcn_mfma_f32_16x16x32_f16(ah, bl1, ac[1][m], 0, 0, 0);
            ac[1][m] = __builtin_amdgcn_mfma_f32_16x16x32_f16(al, bh1, ac[1][m], 0, 0, 0);
        }
        ca0 = na0; ca1 = na1; cb0 = nb0; cb1 = nb1;
    }

    // store fp32 partials, fully coalesced: part[(kc*4+m)*NT + tok][16]
    #pragma unroll
    for (int tt = 0; tt < 2; ++tt) {
        const int tok = t0 + tt * 16 + c;
        #pragma unroll
        for (int m = 0; m < 4; ++m) {
            f32x4 p;
            #pragma unroll
            for (int r = 0; r < 4; ++r) p[r] = am[tt][m][r] + ac[tt][m][r] * (1.f / 2048.f);
            *(f32x4*)&part[(((size_t)(kc * 4 + m) * NT + tok) << 4) + g * 4] = p;
        }
    }
}

// ---- phase 2: one wave per 16 tokens; unrolled independent loads; NO global atomics ----
template<int S>
__global__ __launch_bounds__(64) void router_top(const float* __restrict__ part,
                                                 const float* __restrict__ bias,
                                                 float* __restrict__ out,
                                                 float* __restrict__ psum_part,
                                                 float* __restrict__ cnt_part) {
    __shared__ float cnt[E];
    const int lane = threadIdx.x;
    const int g    = lane >> 4;
    const int c    = lane & 15;
    const int wid  = blockIdx.x;
    const int tok  = wid * 16 + c;

    cnt[lane] = 0.f;

    float lg[4][4];
    #pragma unroll
    for (int m = 0; m < 4; ++m) {
        f32x4 q[S];
        #pragma unroll
        for (int kc = 0; kc < S; ++kc)
            q[kc] = *(const f32x4*)&part[(((size_t)(kc * 4 + m) * NT + tok) << 4) + g * 4];
        f32x4 s = q[0];
        #pragma unroll
        for (int kc = 1; kc < S; ++kc)
            #pragma unroll
            for (int r = 0; r < 4; ++r) s[r] += q[kc][r];
        #pragma unroll
        for (int r = 0; r < 4; ++r) lg[m][r] = s[r] + bias[m * 16 + g * 4 + r];
    }

    // local top-2 over this lane's 16 experts
    float v1 = -3.4e38f, v2 = -3.4e38f; int i1 = 0, i2 = 0;
    #pragma unroll
    for (int m = 0; m < 4; ++m)
        #pragma unroll
        for (int r = 0; r < 4; ++r) {
            const float v = lg[m][r];
            const int   e = m * 16 + g * 4 + r;
            if (v > v1) { v2 = v1; i2 = i1; v1 = v; i1 = e; }
            else if (v > v2) { v2 = v; i2 = e; }
        }
    // merge across the 4 lanes (g) holding this token
    #pragma unroll
    for (int mask = 16; mask <= 32; mask <<= 1) {
        const float ov1 = __shfl_xor(v1, mask, 64); const int oi1 = __shfl_xor(i1, mask, 64);
        const float ov2 = __shfl_xor(v2, mask, 64); const int oi2 = __shfl_xor(i2, mask, 64);
        const bool oTop = (ov1 > v1) || (ov1 == v1 && oi1 < i1);
        if (oTop) {
            const bool k2 = (v1 > ov2) || (v1 == ov2 && i1 < oi2);
            v2 = k2 ? v1 : ov2; i2 = k2 ? i1 : oi2;
            v1 = ov1; i1 = oi1;
        } else {
            const bool k2 = (ov1 > v2) || (ov1 == v2 && oi1 < i2);
            v2 = k2 ? ov1 : v2; i2 = k2 ? oi1 : i2;
        }
    }

    // softmax (max = v1)
    float s = 0.f;
    #pragma unroll
    for (int m = 0; m < 4; ++m)
        #pragma unroll
        for (int r = 0; r < 4; ++r) { lg[m][r] = expf(lg[m][r] - v1); s += lg[m][r]; }
    s += __shfl_xor(s, 16, 64);
    s += __shfl_xor(s, 32, 64);
    const float inv = 1.f / s;

    // normalized probs -> per-expert sums across this wave's 16 tokens
    #pragma unroll
    for (int m = 0; m < 4; ++m)
        #pragma unroll
        for (int r = 0; r < 4; ++r) {
            lg[m][r] *= inv;
            #pragma unroll
            for (int mask = 1; mask <= 8; mask <<= 1)
                lg[m][r] += __shfl_xor(lg[m][r], mask, 64);
        }
    if (c == 0) {
        #pragma unroll
        for (int m = 0; m < 4; ++m)
            #pragma unroll
            for (int r = 0; r < 4; ++r)
                psum_part[wid * E + m * 16 + g * 4 + r] = lg[m][r];
    }
    if (g == 0) {   // one leader lane per token
        const float p2 = expf(v2 - v1) * inv;
        out[tok * 2 + 0] = (float)i1;
        out[tok * 2 + 1] = (float)i2;
        out[2 * NT + tok * 2 + 0] = inv;     // p1 = exp(0)/s
        out[2 * NT + tok * 2 + 1] = p2;
        atomicAdd(&cnt[i1], 1.f);            // LDS atomic, wave-local
        atomicAdd(&cnt[i2], 1.f);
    }
    __syncthreads();
    cnt_part[wid * E + lane] = cnt[lane];
}

// ---- final: reduce per-wave partials, compute aux loss ----
__global__ __launch_bounds__(256) void router_aux(const float* __restrict__ psum_part,
                                                  const float* __restrict__ cnt_part,
                                                  float* __restrict__ out) {
    __shared__ float sp[E], sc[E];
    const int t = threadIdx.x;
    if (t < 128) {
        const float* src = (t < E) ? (psum_part + t) : (cnt_part + (t - E));
        float s = 0.f;
        #pragma unroll 8
        for (int w = 0; w < NW; ++w) s += src[(size_t)w * E];
        if (t < E) sp[t] = s; else sc[t - E] = s;
    }
    __syncthreads();
    if (t < E) {
        float v = sp[t] * sc[t] * (1.0f / NT) * (1.0f / NT);
        #pragma unroll
        for (int off = 32; off > 0; off >>= 1) v += __shfl_down(v, off);
        if (t == 0) out[NT * 2 * 2] = (float)E * v;
    }
}

extern "C" void kernel_launch(void* const* d_in, const int* in_sizes, int n_in,
                              void* d_out, int out_size, void* d_ws, size_t ws_size,
                              hipStream_t stream) {
    const float* x = (const float*)d_in[0];
    const float* W = (const float*)d_in[1];
    const float* b = (const float*)d_in[2];
    float* out = (float*)d_out;

    // ws: | wpanes 512KB | psum_part 256KB | cnt_part 256KB | part S*4MB |
    char* base = (char*)d_ws;
    _Float16* wthi = (_Float16*)base;
    _Float16* wtlo = wthi + (size_t)D * E;
    float* psum_part = (float*)(base + 2 * (size_t)D * E * sizeof(_Float16));
    float* cnt_part  = psum_part + (size_t)NW * E;
    float* part      = cnt_part + (size_t)NW * E;
    const size_t head = (char*)part - base;

    int S = 8;   // K-split factor; shrink if workspace is small
    while (S > 1 && head + (size_t)S * NT * E * sizeof(float) > ws_size) S >>= 1;

    router_prep<<<dim3(128), dim3(256), 0, stream>>>(W, wthi, wtlo, D / S);
    const int nblk = (NT / 32) * S / 4;
    switch (S) {
        case 8:
            router_gemm<8><<<dim3(nblk), dim3(256), 0, stream>>>(x, wthi, wtlo, part);
            router_top<8><<<dim3(NW), dim3(64), 0, stream>>>(part, b, out, psum_part, cnt_part);
            break;
        case 4:
            router_gemm<4><<<dim3(nblk), dim3(256), 0, stream>>>(x, wthi, wtlo, part);
            router_top<4><<<dim3(NW), dim3(64), 0, stream>>>(part, b, out, psum_part, cnt_part);
            break;
        case 2:
            router_gemm<2><<<dim3(nblk), dim3(256), 0, stream>>>(x, wthi, wtlo, part);
            router_top<2><<<dim3(NW), dim3(64), 0, stream>>>(part, b, out, psum_part, cnt_part);
            break;
        default:
            router_gemm<1><<<dim3(nblk), dim3(256), 0, stream>>>(x, wthi, wtlo, part);
            router_top<1><<<dim3(NW), dim3(64), 0, stream>>>(part, b, out, psum_part, cnt_part);
            break;
    }
    router_aux<<<dim3(1), dim3(256), 0, stream>>>(psum_part, cnt_part, out);
}

// Round 7
// 54.290 us; speedup vs baseline: 3.5057x; 1.7068x over previous
//
#include <hip/hip_runtime.h>

#define NT 16384
#define D  2048
#define E  64
#define KCH 512           // K-chunk per wave (4 waves = full K)
#define TPC (KCH / 32)    // 16 k-tiles per chunk
#define NBLK (NT / 32)    // 512 blocks

typedef _Float16 half8 __attribute__((ext_vector_type(8)));
typedef float f32x4 __attribute__((ext_vector_type(4)));

// ---- prep: W[k][e] fp32 -> W^T hi/lo panes in MFMA-fragment order ----
// pane offset(k,e) = (((kc*TPC + t)*4 + m)*16 + c)*32 + g*8 + j
__global__ __launch_bounds__(256) void router_prep(const float* __restrict__ W,
                                                   _Float16* __restrict__ wthi,
                                                   _Float16* __restrict__ wtlo) {
    const int id  = blockIdx.x * 256 + threadIdx.x;  // 0..32767
    const int k   = id >> 4;
    const int e4  = (id & 15) << 2;
    const int kc  = k / KCH;
    const int kr  = k % KCH;
    const int t   = kr >> 5;
    const int g   = (kr >> 3) & 3;
    const int j   = kr & 7;
    const float4 v = *(const float4*)&W[(size_t)k * E + e4];
    const float vv[4] = {v.x, v.y, v.z, v.w};
    #pragma unroll
    for (int i = 0; i < 4; ++i) {
        const int e = e4 + i;
        const int m = e >> 4, c = e & 15;
        const size_t off = ((((size_t)(kc * TPC + t) * 4 + m) * 16 + c) * 32) + g * 8 + j;
        float hf = (float)(_Float16)vv[i];
        hf = (fabsf(hf) < 6.1035156e-5f) ? 0.f : hf;   // FTZ guard
        wthi[off] = (_Float16)hf;
        wtlo[off] = (_Float16)((vv[i] - hf) * 2048.f);
    }
}

// ---- fused: GEMM (4 waves split K) + LDS reduce + top2/softmax epilogue ----
__global__ __launch_bounds__(256, 2) void router_fused(const float* __restrict__ x,
                                                       const _Float16* __restrict__ wthi,
                                                       const _Float16* __restrict__ wtlo,
                                                       const float* __restrict__ bias,
                                                       float* __restrict__ out,
                                                       float* __restrict__ psum_part,
                                                       float* __restrict__ cnt_part) {
    __shared__ __align__(16) float red[4][2][16][68];  // [kc][tt][c][e pad 68] = 34.8KB
    __shared__ float cnt[E];

    const int tid  = threadIdx.x;
    const int lane = tid & 63;
    const int w    = tid >> 6;     // wave = K-chunk 0..3
    const int g    = lane >> 4;
    const int c    = lane & 15;
    const int t0   = blockIdx.x * 32;

    if (tid < E) cnt[tid] = 0.f;

    const float* xp0 = &x[(size_t)(t0 + c) * D + w * KCH + g * 8];
    const float* xp1 = &x[(size_t)(t0 + 16 + c) * D + w * KCH + g * 8];
    const _Float16* whp = &wthi[(size_t)w * TPC * 2048 + c * 32 + g * 8];
    const _Float16* wlp = &wtlo[(size_t)w * TPC * 2048 + c * 32 + g * 8];

    f32x4 am[2][4], ac[2][4];
    #pragma unroll
    for (int tt = 0; tt < 2; ++tt)
        #pragma unroll
        for (int m = 0; m < 4; ++m) {
            am[tt][m] = (f32x4){0.f, 0.f, 0.f, 0.f};
            ac[tt][m] = (f32x4){0.f, 0.f, 0.f, 0.f};
        }

    float4 ca0 = *(const float4*)xp0, ca1 = *(const float4*)(xp0 + 4);
    float4 cb0 = *(const float4*)xp1, cb1 = *(const float4*)(xp1 + 4);

    #pragma unroll 1
    for (int t = 0; t < TPC; ++t) {
        float4 na0, na1, nb0, nb1;
        if (t + 1 < TPC) {   // uniform scalar branch; prefetch next x tile
            na0 = *(const float4*)(xp0 + (t + 1) * 32);
            na1 = *(const float4*)(xp0 + (t + 1) * 32 + 4);
            nb0 = *(const float4*)(xp1 + (t + 1) * 32);
            nb1 = *(const float4*)(xp1 + (t + 1) * 32 + 4);
        }
        half8 bh0, bl0, bh1, bl1;
        {
            const float xv0[8] = {ca0.x, ca0.y, ca0.z, ca0.w, ca1.x, ca1.y, ca1.z, ca1.w};
            const float xv1[8] = {cb0.x, cb0.y, cb0.z, cb0.w, cb1.x, cb1.y, cb1.z, cb1.w};
            #pragma unroll
            for (int j = 0; j < 8; ++j) {
                float h0 = (float)(_Float16)xv0[j];
                bh0[j] = (_Float16)h0;  bl0[j] = (_Float16)((xv0[j] - h0) * 2048.f);
                float h1 = (float)(_Float16)xv1[j];
                bh1[j] = (_Float16)h1;  bl1[j] = (_Float16)((xv1[j] - h1) * 2048.f);
            }
        }
        #pragma unroll
        for (int m = 0; m < 4; ++m) {
            const half8 ah = *(const half8*)(whp + (size_t)(t * 4 + m) * 512);
            const half8 al = *(const half8*)(wlp + (size_t)(t * 4 + m) * 512);
            am[0][m] = __builtin_amdgcn_mfma_f32_16x16x32_f16(ah, bh0, am[0][m], 0, 0, 0);
            ac[0][m] = __builtin_amdgcn_mfma_f32_16x16x32_f16(ah, bl0, ac[0][m], 0, 0, 0);
            ac[0][m] = __builtin_amdgcn_mfma_f32_16x16x32_f16(al, bh0, ac[0][m], 0, 0, 0);
            am[1][m] = __builtin_amdgcn_mfma_f32_16x16x32_f16(ah, bh1, am[1][m], 0, 0, 0);
            ac[1][m] = __builtin_amdgcn_mfma_f32_16x16x32_f16(ah, bl1, ac[1][m], 0, 0, 0);
            ac[1][m] = __builtin_amdgcn_mfma_f32_16x16x32_f16(al, bh1, ac[1][m], 0, 0, 0);
        }
        ca0 = na0; ca1 = na1; cb0 = nb0; cb1 = nb1;
    }

    // partials -> LDS
    #pragma unroll
    for (int tt = 0; tt < 2; ++tt)
        #pragma unroll
        for (int m = 0; m < 4; ++m) {
            f32x4 p;
            #pragma unroll
            for (int r = 0; r < 4; ++r) p[r] = am[tt][m][r] + ac[tt][m][r] * (1.f / 2048.f);
            *(f32x4*)&red[w][tt][c][m * 16 + g * 4] = p;
        }
    __syncthreads();

    if (w < 2) {
        // wave w handles tokens t0 + w*16 + c; lane(g,c) experts m*16+g*4+r
        const int tok = t0 + w * 16 + c;
        float lg[4][4];
        #pragma unroll
        for (int m = 0; m < 4; ++m) {
            f32x4 s = *(const f32x4*)&red[0][w][c][m * 16 + g * 4];
            #pragma unroll
            for (int kc = 1; kc < 4; ++kc) {
                const f32x4 q = *(const f32x4*)&red[kc][w][c][m * 16 + g * 4];
                #pragma unroll
                for (int r = 0; r < 4; ++r) s[r] += q[r];
            }
            #pragma unroll
            for (int r = 0; r < 4; ++r) lg[m][r] = s[r] + bias[m * 16 + g * 4 + r];
        }

        // local top-2 over this lane's 16 experts
        float v1 = -3.4e38f, v2 = -3.4e38f; int i1 = 0, i2 = 0;
        #pragma unroll
        for (int m = 0; m < 4; ++m)
            #pragma unroll
            for (int r = 0; r < 4; ++r) {
                const float v = lg[m][r];
                const int   e = m * 16 + g * 4 + r;
                if (v > v1) { v2 = v1; i2 = i1; v1 = v; i1 = e; }
                else if (v > v2) { v2 = v; i2 = e; }
            }
        // merge across the 4 lanes (g) holding this token
        #pragma unroll
        for (int mask = 16; mask <= 32; mask <<= 1) {
            const float ov1 = __shfl_xor(v1, mask, 64); const int oi1 = __shfl_xor(i1, mask, 64);
            const float ov2 = __shfl_xor(v2, mask, 64); const int oi2 = __shfl_xor(i2, mask, 64);
            const bool oTop = (ov1 > v1) || (ov1 == v1 && oi1 < i1);
            if (oTop) {
                const bool k2 = (v1 > ov2) || (v1 == ov2 && i1 < oi2);
                v2 = k2 ? v1 : ov2; i2 = k2 ? i1 : oi2;
                v1 = ov1; i1 = oi1;
            } else {
                const bool k2 = (ov1 > v2) || (ov1 == v2 && oi1 < i2);
                v2 = k2 ? ov1 : v2; i2 = k2 ? oi1 : i2;
            }
        }

        // softmax (max = v1)
        float s = 0.f;
        #pragma unroll
        for (int m = 0; m < 4; ++m)
            #pragma unroll
            for (int r = 0; r < 4; ++r) { lg[m][r] = expf(lg[m][r] - v1); s += lg[m][r]; }
        s += __shfl_xor(s, 16, 64);
        s += __shfl_xor(s, 32, 64);
        const float inv = 1.f / s;

        // normalized probs -> per-expert sums across this wave's 16 tokens
        #pragma unroll
        for (int m = 0; m < 4; ++m)
            #pragma unroll
            for (int r = 0; r < 4; ++r) {
                lg[m][r] *= inv;
                #pragma unroll
                for (int mask = 1; mask <= 8; mask <<= 1)
                    lg[m][r] += __shfl_xor(lg[m][r], mask, 64);
            }
        if (c == 0) {
            const int row = blockIdx.x * 2 + w;
            #pragma unroll
            for (int m = 0; m < 4; ++m)
                #pragma unroll
                for (int r = 0; r < 4; ++r)
                    psum_part[row * E + m * 16 + g * 4 + r] = lg[m][r];
        }
        if (g == 0) {   // one leader lane per token
            const float p2 = expf(v2 - v1) * inv;
            out[tok * 2 + 0] = (float)i1;
            out[tok * 2 + 1] = (float)i2;
            out[2 * NT + tok * 2 + 0] = inv;     // p1 = exp(0)/s
            out[2 * NT + tok * 2 + 1] = p2;
            atomicAdd(&cnt[i1], 1.f);            // LDS atomic, block-local
            atomicAdd(&cnt[i2], 1.f);
        }
    }
    __syncthreads();
    if (tid < E) cnt_part[blockIdx.x * E + tid] = cnt[tid];
}

// ---- parallel column reduce: 128 blocks, one expert-column each ----
__global__ __launch_bounds__(256) void router_aux1(const float* __restrict__ psum_part,
                                                   const float* __restrict__ cnt_part,
                                                   float* __restrict__ sums) {
    __shared__ float buf[256];
    const int j   = blockIdx.x;      // 0..63 psum col, 64..127 cnt col
    const int tid = threadIdx.x;
    float s = 0.f;
    if (j < E) {
        for (int r = tid; r < 2 * NBLK; r += 256) s += psum_part[(size_t)r * E + j];
    } else {
        const int e = j - E;
        for (int r = tid; r < NBLK; r += 256) s += cnt_part[(size_t)r * E + e];
    }
    buf[tid] = s;
    __syncthreads();
    #pragma unroll
    for (int step = 128; step >= 64; step >>= 1) {
        if (tid < step) buf[tid] += buf[tid + step];
        __syncthreads();
    }
    if (tid < 64) {
        float v = buf[tid];
        #pragma unroll
        for (int off = 32; off > 0; off >>= 1) v += __shfl_down(v, off);
        if (tid == 0) sums[j] = v;
    }
}

__global__ __launch_bounds__(64) void router_aux2(const float* __restrict__ sums,
                                                  float* __restrict__ out) {
    const int e = threadIdx.x;
    float v = sums[e] * sums[E + e] * (1.0f / NT) * (1.0f / NT);
    #pragma unroll
    for (int off = 32; off > 0; off >>= 1) v += __shfl_down(v, off);
    if (e == 0) out[NT * 2 * 2] = (float)E * v;
}

extern "C" void kernel_launch(void* const* d_in, const int* in_sizes, int n_in,
                              void* d_out, int out_size, void* d_ws, size_t ws_size,
                              hipStream_t stream) {
    const float* x = (const float*)d_in[0];
    const float* W = (const float*)d_in[1];
    const float* b = (const float*)d_in[2];
    float* out = (float*)d_out;

    // ws: | wthi 256KB | wtlo 256KB | psum_part 256KB | cnt_part 128KB | sums 512B |
    char* base = (char*)d_ws;
    _Float16* wthi = (_Float16*)base;
    _Float16* wtlo = wthi + (size_t)D * E;
    float* psum_part = (float*)(base + 2 * (size_t)D * E * sizeof(_Float16));
    float* cnt_part  = psum_part + (size_t)2 * NBLK * E;
    float* sums      = cnt_part + (size_t)NBLK * E;

    router_prep<<<dim3(128), dim3(256), 0, stream>>>(W, wthi, wtlo);
    router_fused<<<dim3(NBLK), dim3(256), 0, stream>>>(x, wthi, wtlo, b, out,
                                                       psum_part, cnt_part);
    router_aux1<<<dim3(128), dim3(256), 0, stream>>>(psum_part, cnt_part, sums);
    router_aux2<<<dim3(1), dim3(64), 0, stream>>>(sums, out);
}